// Round 7
// baseline (27.607 us; speedup 1.0000x reference)
//
#include <hip/hip_runtime.h>
#include <math.h>

#define NPTS 512
#define DIM  2048
#define MARGIN_F 0.5f
#define KZ 8
#define KCHUNK (DIM / KZ)   // 256

typedef __attribute__((ext_vector_type(4))) float f32x4;
typedef __attribute__((ext_vector_type(8))) short bf16x8;

__device__ inline unsigned short bfr(float f) {
    unsigned int u = __float_as_uint(f);
    u += 0x7FFFu + ((u >> 16) & 1u);   // round-to-nearest-even bf16
    return (unsigned short)(u >> 16);
}

// ---------- kernel 1: split-K Gram partials, f32->bf16 fused into staging.
// EXACT R0 baseline (best measured: 24.98 us).
__global__ __launch_bounds__(256) void gram_kernel(const float* __restrict__ x,
                                                   float* __restrict__ part,
                                                   float* __restrict__ diag) {
    __shared__ unsigned short As[64][72];  // +8 pad
    __shared__ unsigned short Bs[64][72];

    int bx = blockIdx.x, by = blockIdx.y, z = blockIdx.z;
    int tid = threadIdx.x;
    int lr = tid >> 2;            // staging row 0..63
    int lc = (tid & 3) * 16;      // staging col (elements) 0,16,32,48

    const float* arow = x + (size_t)(bx * 64 + lr) * DIM + (size_t)z * KCHUNK + lc;
    const float* brow = x + (size_t)(by * 64 + lr) * DIM + (size_t)z * KCHUNK + lc;

    int w = tid >> 6, lane = tid & 63;
    int wr = (w >> 1) * 32, wc = (w & 1) * 32;
    int fr = lane & 15, ko = (lane >> 4) * 8;

    f32x4 acc[2][2] = {};

    for (int ks = 0; ks < KCHUNK; ks += 64) {
        float4 a0 = *reinterpret_cast<const float4*>(arow + ks);
        float4 a1 = *reinterpret_cast<const float4*>(arow + ks + 4);
        float4 a2 = *reinterpret_cast<const float4*>(arow + ks + 8);
        float4 a3 = *reinterpret_cast<const float4*>(arow + ks + 12);
        float4 b0 = *reinterpret_cast<const float4*>(brow + ks);
        float4 b1 = *reinterpret_cast<const float4*>(brow + ks + 4);
        float4 b2 = *reinterpret_cast<const float4*>(brow + ks + 8);
        float4 b3 = *reinterpret_cast<const float4*>(brow + ks + 12);
        ushort4 ua0 = { bfr(a0.x), bfr(a0.y), bfr(a0.z), bfr(a0.w) };
        ushort4 ua1 = { bfr(a1.x), bfr(a1.y), bfr(a1.z), bfr(a1.w) };
        ushort4 ua2 = { bfr(a2.x), bfr(a2.y), bfr(a2.z), bfr(a2.w) };
        ushort4 ua3 = { bfr(a3.x), bfr(a3.y), bfr(a3.z), bfr(a3.w) };
        ushort4 ub0 = { bfr(b0.x), bfr(b0.y), bfr(b0.z), bfr(b0.w) };
        ushort4 ub1 = { bfr(b1.x), bfr(b1.y), bfr(b1.z), bfr(b1.w) };
        ushort4 ub2 = { bfr(b2.x), bfr(b2.y), bfr(b2.z), bfr(b2.w) };
        ushort4 ub3 = { bfr(b3.x), bfr(b3.y), bfr(b3.z), bfr(b3.w) };
        *reinterpret_cast<ushort4*>(&As[lr][lc])      = ua0;
        *reinterpret_cast<ushort4*>(&As[lr][lc + 4])  = ua1;
        *reinterpret_cast<ushort4*>(&As[lr][lc + 8])  = ua2;
        *reinterpret_cast<ushort4*>(&As[lr][lc + 12]) = ua3;
        *reinterpret_cast<ushort4*>(&Bs[lr][lc])      = ub0;
        *reinterpret_cast<ushort4*>(&Bs[lr][lc + 4])  = ub1;
        *reinterpret_cast<ushort4*>(&Bs[lr][lc + 8])  = ub2;
        *reinterpret_cast<ushort4*>(&Bs[lr][lc + 12]) = ub3;
        __syncthreads();
#pragma unroll
        for (int kc = 0; kc < 2; ++kc) {
            bf16x8 fa0 = *reinterpret_cast<const bf16x8*>(&As[wr + fr][kc * 32 + ko]);
            bf16x8 fa1 = *reinterpret_cast<const bf16x8*>(&As[wr + 16 + fr][kc * 32 + ko]);
            bf16x8 fb0 = *reinterpret_cast<const bf16x8*>(&Bs[wc + fr][kc * 32 + ko]);
            bf16x8 fb1 = *reinterpret_cast<const bf16x8*>(&Bs[wc + 16 + fr][kc * 32 + ko]);
            acc[0][0] = __builtin_amdgcn_mfma_f32_16x16x32_bf16(fa0, fb0, acc[0][0], 0, 0, 0);
            acc[0][1] = __builtin_amdgcn_mfma_f32_16x16x32_bf16(fa0, fb1, acc[0][1], 0, 0, 0);
            acc[1][0] = __builtin_amdgcn_mfma_f32_16x16x32_bf16(fa1, fb0, acc[1][0], 0, 0, 0);
            acc[1][1] = __builtin_amdgcn_mfma_f32_16x16x32_bf16(fa1, fb1, acc[1][1], 0, 0, 0);
        }
        __syncthreads();
    }

    float* pg = part + (size_t)z * NPTS * NPTS;
    int rbase = bx * 64 + wr + ((lane >> 4) << 2);  // C/D: row = (lane>>4)*4 + reg
    int cbase = by * 64 + wc + fr;                  //      col = lane&15
#pragma unroll
    for (int m = 0; m < 2; ++m)
#pragma unroll
        for (int n = 0; n < 2; ++n) {
            f32x4 v = acc[m][n];
#pragma unroll
            for (int j = 0; j < 4; ++j)
                pg[(size_t)(rbase + m * 16 + j) * NPTS + (cbase + n * 16)] = v[j];
        }

    if (bx == by && wr == wc && (fr >> 2) == (lane >> 4)) {
        int j = fr & 3;
#pragma unroll
        for (int m = 0; m < 2; ++m)
            diag[(size_t)z * NPTS + bx * 64 + wr + m * 16 + fr] = acc[m][m][j];
    }
}

// ---------- overhead probe: 1 block, 64 threads, provably-never-taken store.
// Adds exactly one dispatch of ~zero work; measures per-dispatch fixed cost.
__global__ __launch_bounds__(64) void probe_kernel(unsigned int* __restrict__ p) {
    if (threadIdx.x == 1024u) p[0] = 1u;   // blockDim=64 -> never executes
}

// ---------- kernel 2: per-anchor hinge; norms from compact diag ----------
__global__ __launch_bounds__(256) void triplet_kernel(const float* __restrict__ part,
                                                      const float* __restrict__ diag,
                                                      const int* __restrict__ traw,
                                                      float* __restrict__ psum,
                                                      unsigned int* __restrict__ pcnt) {
    __shared__ float drow[NPTS];
    __shared__ float sqv[NPTS];
    __shared__ int   tl[NPTS];
    __shared__ int   pos[NPTS];
    __shared__ int   is64;
    __shared__ unsigned long long wmask[8];
    __shared__ float wsum[4];
    __shared__ unsigned int wcnt[4];

    int a = blockIdx.x, tid = threadIdx.x;
    int lane = tid & 63, wid = tid >> 6;
    if (tid == 0) is64 = 1;
    __syncthreads();

    for (int i = tid; i < NPTS / 2; i += 256)
        if (traw[2 * i + 1] != 0) is64 = 0;
    __syncthreads();
    if (is64) { for (int i = tid; i < NPTS; i += 256) tl[i] = traw[2 * i]; }
    else      { for (int i = tid; i < NPTS; i += 256) tl[i] = traw[i]; }

    for (int j = tid; j < NPTS; j += 256) {
        float s = 0.f;
#pragma unroll
        for (int z = 0; z < KZ; ++z) s += diag[(size_t)z * NPTS + j];
        sqv[j] = s;
    }
    __syncthreads();

    const size_t PL = (size_t)NPTS * NPTS;
    float sqa = sqv[a];
    for (int i = tid; i < NPTS / 4; i += 256) {
        float4 g4 = {0.f, 0.f, 0.f, 0.f};
#pragma unroll
        for (int z = 0; z < KZ; ++z) {
            float4 gz = reinterpret_cast<const float4*>(part + (size_t)z * PL + (size_t)a * NPTS)[i];
            g4.x += gz.x; g4.y += gz.y; g4.z += gz.z; g4.w += gz.w;
        }
        float d2;
        d2 = sqa + sqv[4 * i + 0] - 2.f * g4.x; drow[4 * i + 0] = d2 > 0.f ? sqrtf(d2) : 0.f;
        d2 = sqa + sqv[4 * i + 1] - 2.f * g4.y; drow[4 * i + 1] = d2 > 0.f ? sqrtf(d2) : 0.f;
        d2 = sqa + sqv[4 * i + 2] - 2.f * g4.z; drow[4 * i + 2] = d2 > 0.f ? sqrtf(d2) : 0.f;
        d2 = sqa + sqv[4 * i + 3] - 2.f * g4.w; drow[4 * i + 3] = d2 > 0.f ? sqrtf(d2) : 0.f;
    }
    __syncthreads();

    int ta = tl[a];
    unsigned long long bal[2];
    bool m[2];
#pragma unroll
    for (int p = 0; p < 2; ++p) {
        int j = p * 256 + tid;
        m[p] = (tl[j] == ta) && (j != a);
        bal[p] = __ballot(m[p]);
        if (lane == 0) wmask[p * 4 + wid] = bal[p];
    }
    __syncthreads();
    int np = 0;
#pragma unroll
    for (int k = 0; k < 8; ++k) np += __popcll(wmask[k]);
#pragma unroll
    for (int p = 0; p < 2; ++p) {
        if (m[p]) {
            int widx = p * 4 + wid, base = 0;
            for (int k = 0; k < widx; ++k) base += __popcll(wmask[k]);
            base += __popcll(bal[p] & ((1ull << lane) - 1ull));
            pos[base] = p * 256 + tid;
        }
    }
    __syncthreads();

    float sum = 0.f;
    unsigned int cnt = 0;
    int tot = np << 9;
    for (int idx = tid; idx < tot; idx += 256) {
        int p = pos[idx >> 9];
        int n = idx & (NPTS - 1);
        if (tl[n] != ta) {
            float v = drow[p] - drow[n] + MARGIN_F;
            if (v > 0.f) { sum += v; cnt++; }
        }
    }

    for (int off = 32; off; off >>= 1) {
        sum += __shfl_down(sum, off);
        cnt += __shfl_down(cnt, off);
    }
    if (lane == 0) { wsum[wid] = sum; wcnt[wid] = cnt; }
    __syncthreads();
    if (tid == 0) {
        psum[a] = wsum[0] + wsum[1] + wsum[2] + wsum[3];
        pcnt[a] = wcnt[0] + wcnt[1] + wcnt[2] + wcnt[3];
    }
}

// ---------- kernel 3: final reduction over 512 per-anchor partials ----------
__global__ __launch_bounds__(256) void finalize_kernel(const float* __restrict__ psum,
                                                       const unsigned int* __restrict__ pcnt,
                                                       float* __restrict__ out) {
    int tid = threadIdx.x;
    float s = psum[tid] + psum[tid + 256];
    unsigned int c = pcnt[tid] + pcnt[tid + 256];
    for (int off = 32; off; off >>= 1) {
        s += __shfl_down(s, off);
        c += __shfl_down(c, off);
    }
    __shared__ float ws[4];
    __shared__ unsigned int wc[4];
    int lane = tid & 63, wid = tid >> 6;
    if (lane == 0) { ws[wid] = s; wc[wid] = c; }
    __syncthreads();
    if (tid == 0) {
        float tot = ws[0] + ws[1] + ws[2] + ws[3];
        unsigned int cnt = wc[0] + wc[1] + wc[2] + wc[3];
        out[0] = tot / (float)(cnt ? cnt : 1u);
    }
}

extern "C" void kernel_launch(void* const* d_in, const int* in_sizes, int n_in,
                              void* d_out, int out_size, void* d_ws, size_t ws_size,
                              hipStream_t stream) {
    const float* x = (const float*)d_in[0];
    const int* t = (const int*)d_in[1];
    float* out = (float*)d_out;

    char* ws = (char*)d_ws;
    const size_t OFF_PART = 0;                                  // 8 MiB (8 planes)
    const size_t OFF_DIAG = (size_t)KZ * NPTS * NPTS * 4;       // 16 KiB
    const size_t OFF_PSUM = OFF_DIAG + (size_t)KZ * NPTS * 4;   // 2 KiB
    const size_t OFF_PCNT = OFF_PSUM + 2048;                    // 2 KiB

    float* part        = (float*)(ws + OFF_PART);
    float* diag        = (float*)(ws + OFF_DIAG);
    float* psum        = (float*)(ws + OFF_PSUM);
    unsigned int* pcnt = (unsigned int*)(ws + OFF_PCNT);

    gram_kernel<<<dim3(8, 8, KZ), 256, 0, stream>>>(x, part, diag);
    probe_kernel<<<1, 64, 0, stream>>>(pcnt);                   // overhead probe #1
    triplet_kernel<<<NPTS, 256, 0, stream>>>(part, diag, t, psum, pcnt);
    probe_kernel<<<1, 64, 0, stream>>>(pcnt);                   // overhead probe #2
    finalize_kernel<<<1, 256, 0, stream>>>(psum, pcnt, out);
}